// Round 15
// baseline (395.324 us; speedup 1.0000x reference)
//
#include <hip/hip_runtime.h>

// R15: ABLATION, DCE-PROOFED (R14's abl was folded away: LDS never written ->
// reads undef -> SAD deleted; rule #17). Here the ablation kernel seeds LDS
// with 9 dynamic-index ds_writes per thread (compiler cannot prove any read
// unwritten -> no folding), then runs the byte-identical R8 compute stream.
// The exact R8 kernel runs LAST, overwriting all outputs -> absmax 0.
// Readout: C(compute-only cost) = bench_dur_us - 211 - ~2.

namespace {
constexpr int BLKi  = 16;
constexpr int NSDi  = 4;
constexpr int ND    = 9;
constexpr int NDISP = 81;
constexpr int Nn    = 8;
constexpr int Cc    = 3;
constexpr int Hh    = 1024;
constexpr int Ww    = 1024;
constexpr int BHn   = 64;
constexpr int STRIPW = 64;
constexpr int SW    = 72;
constexpr int SH    = 24;
constexpr int STRIP_FLOATS = Cc * SH * SW;    // 5184
constexpr int STRIP_CHUNKS = STRIP_FLOATS/4;  // 1296
constexpr int TGT_FLOATS   = Cc * BLKi * STRIPW; // 3072
constexpr int TOT_CHUNKS   = STRIP_CHUNKS + TGT_FLOATS / 4; // 2064
constexpr int ITERS        = 9;
constexpr int LDSF         = ITERS * 256 * 4; // 9216 floats
constexpr int MV_SIZE = Nn * 2 * BHn * BHn;   // 65536
constexpr int NWG     = Nn * BHn * (Ww / STRIPW); // 8192
}

typedef const __attribute__((address_space(1))) void* gas_ptr;
typedef __attribute__((address_space(3))) void*       las_ptr;

__global__ void init_kernel(float* __restrict__ out) {
    int i = blockIdx.x * 256 + threadIdx.x;
    if (i < MV_SIZE) out[i] = 0.0f;
}

// ---------------- ablation kernel: R8 with staging -> dummy LDS seed --------
__global__ __launch_bounds__(256, 2) void hbma_comp_abl(
        const float* __restrict__ ref,
        const float* __restrict__ tgt,
        float* __restrict__ pred,
        const float* __restrict__ zsrc) {
    __shared__ float ldsA[LDSF];
    __shared__ float costL[4][NDISP];

    const int tid  = (int)threadIdx.x;
    const int wid  = tid >> 6;
    const int lane = tid & 63;
    const int w    = (int)blockIdx.x;
    const int n    = w >> 10;
    const int rem  = w & 1023;
    const int Y0   = (rem >> 4) * BLKi;
    const int X0   = (rem & 15) * STRIPW;
    float* predn = pred + (size_t)n * Cc * Hh * Ww;

    // ---- DCE-proof LDS seed: dynamic-index writes, trivial cost ----
    #pragma unroll
    for (int i = 0; i < ITERS; ++i)
        ldsA[i * 1024 + ((tid * 5 + i * 37) & 1023)] = (float)(tid + i);
    __syncthreads();

    const int col  = lane & 15;
    const int g    = lane >> 4;
    const int d0   = g * 3;
    const int colS = (wid << 4) + col;
    const float* __restrict__ ldsT = ldsA + STRIP_FLOATS;

    float acc[ND][3];
    #pragma unroll
    for (int j = 0; j < ND; ++j) {
        acc[j][0] = 0.0f; acc[j][1] = 0.0f; acc[j][2] = 0.0f;
    }

    #pragma unroll 1
    for (int c = 0; c < Cc; ++c) {
        float T[BLKi];
        #pragma unroll
        for (int y = 0; y < BLKi; ++y)
            T[y] = ldsT[(c * BLKi + y) * STRIPW + colS];

        #pragma unroll
        for (int r = 0; r < SH; ++r) {
            const float* rp = ldsA + (c * SH + r) * SW + colS + d0;
            const float rv0 = rp[0], rv1 = rp[1], rv2 = rp[2];
            #pragma unroll
            for (int j = 0; j < ND; ++j) {
                const int y = r - j;
                if (y >= 0 && y < BLKi) {
                    const float tv = T[y];
                    acc[j][0] += fabsf(rv0 - tv);
                    acc[j][1] += fabsf(rv1 - tv);
                    acc[j][2] += fabsf(rv2 - tv);
                }
            }
        }
    }

    #pragma unroll
    for (int m = 1; m <= 8; m <<= 1)
        #pragma unroll
        for (int j = 0; j < ND; ++j) {
            acc[j][0] += __shfl_xor(acc[j][0], m, 64);
            acc[j][1] += __shfl_xor(acc[j][1], m, 64);
            acc[j][2] += __shfl_xor(acc[j][2], m, 64);
        }

    #pragma unroll
    for (int jj = 0; jj < ND; ++jj) {
        if (g < 3 && col == jj) {
            costL[wid][jj * ND + d0 + 0] = acc[jj][0];
            costL[wid][jj * ND + d0 + 1] = acc[jj][1];
            costL[wid][jj * ND + d0 + 2] = acc[jj][2];
        }
    }
    asm volatile("s_waitcnt lgkmcnt(0)" ::: "memory");

    float bc = costL[wid][lane];
    int   bj = lane;
    if (lane < NDISP - 64) {
        float c2 = costL[wid][lane + 64];
        if (c2 < bc) { bc = c2; bj = lane + 64; }
    }
    #pragma unroll
    for (int m = 1; m <= 32; m <<= 1) {
        float oc = __shfl_xor(bc, m, 64);
        int   oi = __shfl_xor(bj, m, 64);
        if (oc < bc || (oc == bc && oi < bj)) { bc = oc; bj = oi; }
    }
    const int by = bj / ND;
    const int bx = bj % ND;

    #pragma unroll 1
    for (int c = 0; c < Cc; ++c) {
        #pragma unroll
        for (int yy = 0; yy < 4; ++yy) {
            const int y = (g << 2) + yy;
            const float v = ldsA[(c * SH + y + by) * SW + colS + bx];
            predn[(c << 20) + ((Y0 + y) << 10) + X0 + colS] = v;
        }
    }
}

// ---------------- exact R8 kernel (runs last; produces correct output) ------
__global__ __launch_bounds__(256, 2) void hbma_kernel(
        const float* __restrict__ ref,
        const float* __restrict__ tgt,
        float* __restrict__ pred,
        const float* __restrict__ zsrc) {
    __shared__ float ldsA[LDSF];
    __shared__ float costL[4][NDISP];

    const int tid  = (int)threadIdx.x;
    const int wid  = tid >> 6;
    const int lane = tid & 63;
    const int w    = (int)blockIdx.x;
    const int n    = w >> 10;
    const int rem  = w & 1023;
    const int Y0   = (rem >> 4) * BLKi;
    const int X0   = (rem & 15) * STRIPW;
    const float* refn  = ref  + (size_t)n * Cc * Hh * Ww;
    const float* tgtn  = tgt  + (size_t)n * Cc * Hh * Ww;
    float*       predn = pred + (size_t)n * Cc * Hh * Ww;

    #pragma unroll
    for (int i = 0; i < ITERS; ++i) {
        const int ck = i * 256 + tid;
        if (ck < TOT_CHUNKS) {
            const float* src;
            if (ck < STRIP_CHUNKS) {
                const int c    = ck / (SH * SW / 4);
                const int rm   = ck - c * (SH * SW / 4);
                const int r    = rm / (SW / 4);
                const int colc = (rm - r * (SW / 4)) * 4;
                const int gy   = Y0 - NSDi + r;
                const int gx   = X0 - NSDi + colc;
                const bool ok  = ((unsigned)gy < (unsigned)Hh) &&
                                 ((unsigned)gx < (unsigned)Ww);
                src = ok ? (refn + (c << 20) + (gy << 10) + gx) : zsrc;
            } else {
                const int tk   = ck - STRIP_CHUNKS;
                const int c    = tk >> 8;
                const int rm2  = tk & 255;
                const int y    = rm2 >> 4;
                const int colc = (rm2 & 15) * 4;
                src = tgtn + (c << 20) + ((Y0 + y) << 10) + X0 + colc;
            }
            __builtin_amdgcn_global_load_lds((gas_ptr)src,
                    (las_ptr)(ldsA + i * 1024 + (tid & 192) * 4), 16, 0, 0);
        }
    }
    __syncthreads();

    const int col  = lane & 15;
    const int g    = lane >> 4;
    const int d0   = g * 3;
    const int colS = (wid << 4) + col;
    const float* __restrict__ ldsT = ldsA + STRIP_FLOATS;

    float acc[ND][3];
    #pragma unroll
    for (int j = 0; j < ND; ++j) {
        acc[j][0] = 0.0f; acc[j][1] = 0.0f; acc[j][2] = 0.0f;
    }

    #pragma unroll 1
    for (int c = 0; c < Cc; ++c) {
        float T[BLKi];
        #pragma unroll
        for (int y = 0; y < BLKi; ++y)
            T[y] = ldsT[(c * BLKi + y) * STRIPW + colS];

        #pragma unroll
        for (int r = 0; r < SH; ++r) {
            const float* rp = ldsA + (c * SH + r) * SW + colS + d0;
            const float rv0 = rp[0], rv1 = rp[1], rv2 = rp[2];
            #pragma unroll
            for (int j = 0; j < ND; ++j) {
                const int y = r - j;
                if (y >= 0 && y < BLKi) {
                    const float tv = T[y];
                    acc[j][0] += fabsf(rv0 - tv);
                    acc[j][1] += fabsf(rv1 - tv);
                    acc[j][2] += fabsf(rv2 - tv);
                }
            }
        }
    }

    #pragma unroll
    for (int m = 1; m <= 8; m <<= 1)
        #pragma unroll
        for (int j = 0; j < ND; ++j) {
            acc[j][0] += __shfl_xor(acc[j][0], m, 64);
            acc[j][1] += __shfl_xor(acc[j][1], m, 64);
            acc[j][2] += __shfl_xor(acc[j][2], m, 64);
        }

    #pragma unroll
    for (int jj = 0; jj < ND; ++jj) {
        if (g < 3 && col == jj) {
            costL[wid][jj * ND + d0 + 0] = acc[jj][0];
            costL[wid][jj * ND + d0 + 1] = acc[jj][1];
            costL[wid][jj * ND + d0 + 2] = acc[jj][2];
        }
    }
    asm volatile("s_waitcnt lgkmcnt(0)" ::: "memory");

    float bc = costL[wid][lane];
    int   bj = lane;
    if (lane < NDISP - 64) {
        float c2 = costL[wid][lane + 64];
        if (c2 < bc) { bc = c2; bj = lane + 64; }
    }
    #pragma unroll
    for (int m = 1; m <= 32; m <<= 1) {
        float oc = __shfl_xor(bc, m, 64);
        int   oi = __shfl_xor(bj, m, 64);
        if (oc < bc || (oc == bc && oi < bj)) { bc = oc; bj = oi; }
    }
    const int by = bj / ND;
    const int bx = bj % ND;

    #pragma unroll 1
    for (int c = 0; c < Cc; ++c) {
        #pragma unroll
        for (int yy = 0; yy < 4; ++yy) {
            const int y = (g << 2) + yy;
            const float v = ldsA[(c * SH + y + by) * SW + colS + bx];
            predn[(c << 20) + ((Y0 + y) << 10) + X0 + colS] = v;
        }
    }
}

extern "C" void kernel_launch(void* const* d_in, const int* in_sizes, int n_in,
                              void* d_out, int out_size, void* d_ws, size_t ws_size,
                              hipStream_t stream) {
    const float* ref = (const float*)d_in[0];
    const float* tgt = (const float*)d_in[1];
    float* out = (float*)d_out;

    init_kernel<<<dim3((MV_SIZE + 255) / 256), dim3(256), 0, stream>>>(out);

    // ablation first (garbage output; LDS seeded so nothing folds)...
    hbma_comp_abl<<<dim3(NWG), dim3(256), 0, stream>>>(ref, tgt, out + MV_SIZE, out);
    // ...then exact R8, which overwrites ALL outputs -> correct final state.
    hbma_kernel<<<dim3(NWG), dim3(256), 0, stream>>>(ref, tgt, out + MV_SIZE, out);
}